// Round 12
// baseline (448.451 us; speedup 1.0000x reference)
//
#include <hip/hip_runtime.h>
#include <math.h>

#define HID 50
#define TT  512
#define BT  16      // batch per block (= MFMA N)
#define NCW 4       // 4 waves; tiles {3,3,3,4}; wave0 = y chore, wave1 = x chore
#define HS  72      // H plane row stride in shorts
#define L2E 1.44269504088896f

typedef __attribute__((ext_vector_type(8))) short bf16x8;
typedef __attribute__((ext_vector_type(4))) float f32x4;

__device__ __forceinline__ unsigned short bf16_rtne(float f) {
    unsigned u = __float_as_uint(f);
    u = (u + 0x7FFFu + ((u >> 16) & 1u)) >> 16;
    return (unsigned short)u;
}
__device__ __forceinline__ float bf16_f32(unsigned short s) {
    return __uint_as_float(((unsigned)s) << 16);
}

// R11: s_barrier ELIMINATED from the 512-step loop. Cross-wave sync is LDS
// progress flags: flags[w] = #steps wave w completed. To compute step t a wave
// spin-polls min(flags) >= t (h_{t-1} posted by all), then proceeds
// immediately -- no block-wide rendezvous/restart convoy.
// WAR safety proof: poll(min>=t) => every wave completed step t-1, and each
// flag post follows a __threadfence_block (lgkmcnt(0)) => ALL DS ops (reads
// AND writes) of steps <= t-1 retired. Step t writes Hh[1-p]; the only reader
// of Hh[1-p] was step t-1 (done) and the next reader polls min >= t+1 which
// requires this wave's own post. Double buffer suffices. Waves of one
// workgroup are co-resident => spin cannot deadlock.
// Numerics identical to R9/R10 (absmax 4.88e-4): single-plane A pre-scaled by
// log2e / 2*log2e, split-precision bias + W_ih*x via K-slots, fused forms
//   sig(i)*tanh(g) = (Eg-1)*rcp((1+Ei)(1+Eg)), h = (Ec-1)*rcp((1+Eo)(1+Ec)).
// K-slots: 0..49 = s*W_hh | 50 = (s*Wih)_hi (x_hi) | 51 = (s*bias)_hi (1.0)
//          52 = (s*Wih)_hi (x_lo) | 53 = (s*bias)_lo (1.0) | 54 = (s*Wih)_lo (x_hi)
__global__ __launch_bounds__(256) void lstm_flag_kernel(
    const float* __restrict__ x,      // [B, T]
    const float* __restrict__ W_ih,   // [200, 1]
    const float* __restrict__ W_hh,   // [200, 50]
    const float* __restrict__ b_ih,   // [200]
    const float* __restrict__ b_hh,   // [200]
    const float* __restrict__ W_out,  // [1, 50]
    const float* __restrict__ b_out,  // [1]
    float* __restrict__ out)          // [B, T]
{
    const int tid  = threadIdx.x;
    const int lane = tid & 63;
    const int wv   = tid >> 6;       // 0..3
    const int col  = lane & 15;      // A-m / B-n(batch) / D-col(batch)
    const int quad = lane >> 4;      // k-octet / D row-group

    __shared__ __align__(16) unsigned short Hh[2][BT][HS];
    __shared__ unsigned xk[TT][BT + 1];   // packed x: hi | lo<<16
    __shared__ float    yl[TT][BT + 1];   // y staging
    __shared__ float    ypart[2][NCW][17];
    __shared__ unsigned flags[NCW];       // progress counters

    // zero both H buffers (k-slots 55..63 + pads stay 0)
    for (int i = tid; i < 2 * BT * HS; i += 256)
        (&Hh[0][0][0])[i] = 0;
    if (tid < NCW) flags[tid] = 0;

    // stage + convert x (coalesced float4; one-time)
    {
        const float4* xg = (const float4*)(x + (size_t)blockIdx.x * BT * TT);
        #pragma unroll
        for (int pk = 0; pk < (BT * TT / 4) / 256; ++pk) {   // 8 iters
            const int idx = pk * 256 + tid;                  // float4 index
            const float4 v = xg[idx];
            const int b = (idx * 4) >> 9;
            const int t = (idx * 4) & 511;
            const float f[4] = {v.x, v.y, v.z, v.w};
            #pragma unroll
            for (int j = 0; j < 4; ++j) {
                const unsigned short hx = bf16_rtne(f[j]);
                const unsigned short lx = bf16_rtne(f[j] - bf16_f32(hx));
                xk[t + j][b] = (unsigned)hx | ((unsigned)lx << 16);
            }
        }
    }

    const int base = wv * 3;                    // first tile
    const int cnt  = 3 + (wv == 3 ? 1 : 0);     // tiles owned {3,3,3,4}

    // persistent A fragments (single plane, pre-scaled rows) -- same as R9/R10
    bf16x8 Ah[4][2];
    float c[4]  = {0.f, 0.f, 0.f, 0.f};
    float wo[4] = {0.f, 0.f, 0.f, 0.f};
    #pragma unroll
    for (int i = 0; i < 4; ++i) {
        #pragma unroll
        for (int kk = 0; kk < 2; ++kk)
            #pragma unroll
            for (int j = 0; j < 8; ++j) Ah[i][kk][j] = 0;
        if (i < cnt) {
            const int gh  = (base + i) * 16 + col;   // g^ row
            const int u   = gh >> 2;
            const int ty  = gh & 3;
            const bool vl = (u < HID);
            const int og  = ty * HID + u;            // original gate row
            const float sc = (ty == 2) ? 2.f * L2E : L2E;  // g-rows: 2*log2e
            #pragma unroll
            for (int kk = 0; kk < 2; ++kk) {
                #pragma unroll
                for (int j = 0; j < 8; ++j) {
                    const int k = kk * 32 + quad * 8 + j;
                    float v = 0.f;
                    if (vl) {
                        if (k < HID)      v = sc * W_hh[og * HID + k];
                        else if (k == 50) v = sc * W_ih[og];
                        else if (k == 51) v = sc * (b_ih[og] + b_hh[og]);
                        else if (k == 52) v = sc * W_ih[og];
                        else if (k == 53) {
                            const float sb = sc * (b_ih[og] + b_hh[og]);
                            v = sb - bf16_f32(bf16_rtne(sb));
                        } else if (k == 54) {
                            const float sw = sc * W_ih[og];
                            v = sw - bf16_f32(bf16_rtne(sw));
                        }
                    }
                    Ah[i][kk][j] = (short)bf16_rtne(v);
                }
            }
            const int uu = (base + i) * 4 + quad;
            wo[i] = (uu < HID) ? W_out[uu] : 0.f;
        }
    }
    const float bo = b_out[0];

    __syncthreads();    // zeroed H + xk + flags visible (outside the loop)

    // one-time: constant 1.0 markers in BOTH buffers; x_0 slots in buffer 0
    if (tid < BT) {
        Hh[0][tid][51] = 0x3F80; Hh[1][tid][51] = 0x3F80;
        Hh[0][tid][53] = 0x3F80; Hh[1][tid][53] = 0x3F80;
        const unsigned w0 = xk[0][tid];
        Hh[0][tid][50] = (unsigned short)(w0 & 0xFFFF);
        Hh[0][tid][52] = (unsigned short)(w0 >> 16);
        Hh[0][tid][54] = (unsigned short)(w0 & 0xFFFF);
    }
    __syncthreads();    // initial state visible; NO barriers after this

    const volatile unsigned* vf = flags;

    for (int t = 0; t < TT; ++t) {
        const int p = t & 1;        // read buffer; write 1-p

        // ---- spin until all waves posted step t-1 (t=0 passes instantly) ----
        unsigned mn;
        do {
            const unsigned f0 = vf[0], f1 = vf[1], f2 = vf[2], f3 = vf[3];
            const unsigned a = f0 < f1 ? f0 : f1;
            const unsigned b = f2 < f3 ? f2 : f3;
            mn = a < b ? a : b;
        } while (mn < (unsigned)t);
        __threadfence_block();      // acquire: no body LDS op floats above poll

        // ---- chores (LDS-only, off other waves' critical path) ----
        if (wv == 0) {
            if (t > 0 && lane < 16) {       // y_{t-1}: reduce -> yl
                float s = bo;
                #pragma unroll
                for (int w = 0; w < NCW; ++w) s += ypart[1 - p][w][lane];
                yl[t - 1][lane] = s;
            }
        } else if (wv == 1) {
            if (lane < 16) {                // x_{t+1} slots into write buffer
                const unsigned w = xk[(t + 1 < TT) ? t + 1 : t][lane];
                Hh[1 - p][lane][50] = (unsigned short)(w & 0xFFFF);
                Hh[1 - p][lane][52] = (unsigned short)(w >> 16);
                Hh[1 - p][lane][54] = (unsigned short)(w & 0xFFFF);
            }
        }

        // ---- compute ----
        const unsigned short* hrow = &Hh[p][col][0];
        const bf16x8 B0 = *(const bf16x8*)&hrow[quad * 8];
        const bf16x8 B1 = *(const bf16x8*)&hrow[32 + quad * 8];

        float psum = 0.f;
        #pragma unroll
        for (int i = 0; i < 4; ++i) {
            if (i < cnt) {
                f32x4 acc = {0.f, 0.f, 0.f, 0.f};
                acc = __builtin_amdgcn_mfma_f32_16x16x32_bf16(Ah[i][0], B0, acc, 0, 0, 0);
                acc = __builtin_amdgcn_mfma_f32_16x16x32_bf16(Ah[i][1], B1, acc, 0, 0, 0);
                // acc = scaled preacts {i', f', g', o'} of unit u, batch col
                const int u = (base + i) * 4 + quad;
                const float Ei = __builtin_amdgcn_exp2f(-acc.x);
                const float Ef = __builtin_amdgcn_exp2f(-acc.y);
                const float Eg = __builtin_amdgcn_exp2f(acc.z);
                const float Eo = __builtin_amdgcn_exp2f(-acc.w);
                const float sf = __builtin_amdgcn_rcpf(1.f + Ef);
                const float P  = (Eg - 1.f) *
                                 __builtin_amdgcn_rcpf((1.f + Ei) * (1.f + Eg));
                c[i] = fmaf(sf, c[i], P);                    // c_t
                const float Ec = __builtin_amdgcn_exp2f(2.f * L2E * c[i]);
                const float h  = (Ec - 1.f) *
                                 __builtin_amdgcn_rcpf((1.f + Eo) * (1.f + Ec));
                if (u < HID)
                    Hh[1 - p][col][u] = bf16_rtne(h);
                psum = fmaf(h, wo[i], psum);                 // phantom wo = 0
            }
        }
        // per-wave y partial: sum over quad groups
        psum += __shfl_xor(psum, 16);
        psum += __shfl_xor(psum, 32);
        if (lane < 16) ypart[p][wv][lane] = psum;

        // ---- release: drain my DS ops, then post progress ----
        __threadfence_block();      // lgkmcnt(0): h/ypart/x writes retired
        if (lane == 0) ((volatile unsigned*)flags)[wv] = (unsigned)(t + 1);
    }

    __syncthreads();    // all waves done (flags == TT)
    if (wv == 0 && lane < 16) {
        float s = bo;
        #pragma unroll
        for (int w = 0; w < NCW; ++w) s += ypart[(TT - 1) & 1][w][lane];
        yl[TT - 1][lane] = s;
    }
    __syncthreads();
    {
        float* yout = out + (size_t)blockIdx.x * BT * TT;
        #pragma unroll
        for (int pk = 0; pk < BT * TT / 256; ++pk) {   // 32 iters
            const int idx = pk * 256 + tid;            // = b*512 + t
            yout[idx] = yl[idx & 511][idx >> 9];
        }
    }
}

extern "C" void kernel_launch(void* const* d_in, const int* in_sizes, int n_in,
                              void* d_out, int out_size, void* d_ws, size_t ws_size,
                              hipStream_t stream) {
    const float* x     = (const float*)d_in[0];
    const float* W_ih  = (const float*)d_in[1];
    const float* W_hh  = (const float*)d_in[2];
    const float* b_ih  = (const float*)d_in[3];
    const float* b_hh  = (const float*)d_in[4];
    const float* W_out = (const float*)d_in[5];
    const float* b_out = (const float*)d_in[6];
    float* out = (float*)d_out;

    const int B = in_sizes[0] / TT;          // 4096
    lstm_flag_kernel<<<B / BT, 256, 0, stream>>>(x, W_ih, W_hh, b_ih, b_hh,
                                                 W_out, b_out, out);
}

// Round 13
// 321.324 us; speedup vs baseline: 1.3956x; 1.3956x over previous
//
#include <hip/hip_runtime.h>
#include <math.h>

#define HID 50
#define TT  512
#define BT  16      // batch per block (= MFMA N)
#define NCW 7       // compute waves (13 M-tiles: 2,2,2,2,2,2,1); wave 7 = chore
#define HS  72      // H plane row stride in shorts
#define L2E 1.44269504088896f

typedef __attribute__((ext_vector_type(8))) short bf16x8;
typedef __attribute__((ext_vector_type(4))) float f32x4;

__device__ __forceinline__ unsigned short bf16_rtne(float f) {
    unsigned u = __float_as_uint(f);
    u = (u + 0x7FFFu + ((u >> 16) & 1u)) >> 16;
    return (unsigned short)u;
}
__device__ __forceinline__ float bf16_f32(unsigned short s) {
    return __uint_as_float(((unsigned)s) << 16);
}

// R12 = R8's measured-best structure + R9/R10's measured-safe fused math,
// plus a one-rcp common-denominator cell update. Structure: 512 threads,
// waves 0..6 own tiles {2,2,2,2,2,2,1}; wave 7 = chore (global x prefetch via
// register pipeline, global y store); ONE s_barrier per step (cheapest sync
// per R11's flag-regression).
// Math: A single-plane bf16, rows PRE-SCALED by log2e (i,f,o) / 2*log2e (g);
// split precision for bias & W_ih*x via spare K-slots. Activations (7 trans):
//   Ei=2^-i', Ef=2^-f', Eg=2^g', Eo=2^-o'
//   c  = [c*(1+Ei)(1+Eg) + (Eg-1)(1+Ef)] * rcp((1+Ef)(1+Ei)(1+Eg))
//   Ec = 2^(2*log2e*c);  h = (Ec-1) * rcp((1+Eo)(1+Ec))
// K-slots: 0..49 = s*W_hh | 50 = (s*Wih)_hi (x_hi) | 51 = (s*bias)_hi (1.0)
//          52 = (s*Wih)_hi (x_lo) | 53 = (s*bias)_lo (1.0) | 54 = (s*Wih)_lo (x_hi)
__global__ __launch_bounds__(512, 2) void lstm_mfma9_kernel(
    const float* __restrict__ x,      // [B, T]
    const float* __restrict__ W_ih,   // [200, 1]
    const float* __restrict__ W_hh,   // [200, 50]
    const float* __restrict__ b_ih,   // [200]
    const float* __restrict__ b_hh,   // [200]
    const float* __restrict__ W_out,  // [1, 50]
    const float* __restrict__ b_out,  // [1]
    float* __restrict__ out)          // [B, T]
{
    const int tid  = threadIdx.x;
    const int lane = tid & 63;
    const int wv   = tid >> 6;       // 0..7
    const int col  = lane & 15;      // A-m / B-n(batch) / D-col(batch)
    const int quad = lane >> 4;      // k-octet / D row-group

    __shared__ __align__(16) unsigned short Hh[2][BT][HS];
    __shared__ float ypart[2][NCW][17];

    // zero both H buffers (k-slots 55..63 + pads stay 0)
    for (int i = tid; i < 2 * BT * HS; i += 512)
        (&Hh[0][0][0])[i] = 0;

    const int base = wv * 2;                    // first tile of this wave
    const int cnt  = (wv == 6) ? 1 : 2;         // tiles owned (wv < NCW)

    // persistent A fragments (single plane, PRE-SCALED rows)
    bf16x8 Ah[2][2];                            // [tile_i][kk]
    float c[2]  = {0.f, 0.f};
    float wo[2] = {0.f, 0.f};
    if (wv < NCW) {
        #pragma unroll
        for (int i = 0; i < 2; ++i) {
            #pragma unroll
            for (int kk = 0; kk < 2; ++kk)
                #pragma unroll
                for (int j = 0; j < 8; ++j) Ah[i][kk][j] = 0;
            if (i < cnt) {
                const int gh  = (base + i) * 16 + col;   // g^ row
                const int u   = gh >> 2;
                const int ty  = gh & 3;
                const bool vl = (u < HID);
                const int og  = ty * HID + u;            // original gate row
                const float sc = (ty == 2) ? 2.f * L2E : L2E;
                #pragma unroll
                for (int kk = 0; kk < 2; ++kk) {
                    #pragma unroll
                    for (int j = 0; j < 8; ++j) {
                        const int k = kk * 32 + quad * 8 + j;
                        float v = 0.f;
                        if (vl) {
                            if (k < HID)      v = sc * W_hh[og * HID + k];
                            else if (k == 50) v = sc * W_ih[og];
                            else if (k == 51) v = sc * (b_ih[og] + b_hh[og]);
                            else if (k == 52) v = sc * W_ih[og];
                            else if (k == 53) {
                                const float sb = sc * (b_ih[og] + b_hh[og]);
                                v = sb - bf16_f32(bf16_rtne(sb));
                            } else if (k == 54) {
                                const float sw = sc * W_ih[og];
                                v = sw - bf16_f32(bf16_rtne(sw));
                            }
                        }
                        Ah[i][kk][j] = (short)bf16_rtne(v);
                    }
                }
                const int uu = (base + i) * 4 + quad;
                wo[i] = (uu < HID) ? W_out[uu] : 0.f;
            }
        }
    }
    const float bo = b_out[0];
    float* yout = out + (size_t)blockIdx.x * BT * TT;

    // chore-wave x pipeline state (lanes 16..31 own batch b = lane-16)
    const float* xrow = x + (size_t)(blockIdx.x * BT + (lane - 16)) * TT;
    float xa = 0.f;
    if (wv == NCW && lane >= 16 && lane < 32)
        xa = xrow[1];                            // x[b][1] for step t=0's write

    __syncthreads();    // zeroed H visible

    // buffer-0 slots for t=0: x_0 hi/lo + bias-1.0 markers (packed b32 writes)
    if (tid < BT) {
        const float x0 = x[(size_t)(blockIdx.x * BT + tid) * TT];
        const unsigned short hx = bf16_rtne(x0);
        const unsigned short lx = bf16_rtne(x0 - bf16_f32(hx));
        unsigned* row32 = (unsigned*)&Hh[0][tid][0];
        row32[25] = (unsigned)hx | (0x3F80u << 16);   // k=50,51
        row32[26] = (unsigned)lx | (0x3F80u << 16);   // k=52,53
        Hh[0][tid][54] = hx;                          // k=54
    }
    __syncthreads();

    for (int t = 0; t < TT; ++t) {
        const int p = t & 1;        // read buffer; write 1-p

        if (wv < NCW) {
            // ---- compute wave ----
            const unsigned short* hrow = &Hh[p][col][0];
            const bf16x8 B0 = *(const bf16x8*)&hrow[quad * 8];
            const bf16x8 B1 = *(const bf16x8*)&hrow[32 + quad * 8];

            float psum = 0.f;
            #pragma unroll
            for (int i = 0; i < 2; ++i) {
                if (i < cnt) {
                    f32x4 acc = {0.f, 0.f, 0.f, 0.f};
                    acc = __builtin_amdgcn_mfma_f32_16x16x32_bf16(Ah[i][0], B0, acc, 0, 0, 0);
                    acc = __builtin_amdgcn_mfma_f32_16x16x32_bf16(Ah[i][1], B1, acc, 0, 0, 0);
                    // acc = scaled preacts {i', f', g', o'} of unit u, batch col
                    const int u = (base + i) * 4 + quad;
                    const float Ei = __builtin_amdgcn_exp2f(-acc.x);
                    const float Ef = __builtin_amdgcn_exp2f(-acc.y);
                    const float Eg = __builtin_amdgcn_exp2f(acc.z);
                    const float Eo = __builtin_amdgcn_exp2f(-acc.w);
                    const float DIG = (1.f + Ei) * (1.f + Eg);
                    const float DF  = 1.f + Ef;
                    const float num = fmaf(c[i], DIG, (Eg - 1.f) * DF);
                    c[i] = num * __builtin_amdgcn_rcpf(DF * DIG);      // c_t
                    const float Ec = __builtin_amdgcn_exp2f(2.f * L2E * c[i]);
                    const float h  = (Ec - 1.f) *
                                     __builtin_amdgcn_rcpf((1.f + Eo) * (1.f + Ec));
                    if (u < HID)
                        Hh[1 - p][col][u] = bf16_rtne(h);
                    psum = fmaf(h, wo[i], psum);                       // phantom wo = 0
                }
            }
            // per-wave y partial: sum over quad groups
            psum += __shfl_xor(psum, 16);
            psum += __shfl_xor(psum, 32);
            if (lane < 16) ypart[p][wv][lane] = psum;
        } else {
            // ---- chore wave ----
            if (lane < 16) {
                // y_{t-1}: reduce + store (early; retires under compute)
                if (t > 0) {
                    float s = bo;
                    #pragma unroll
                    for (int w = 0; w < NCW; ++w) s += ypart[1 - p][w][lane];
                    yout[(size_t)lane * TT + (t - 1)] = s;
                }
            } else if (lane < 32) {
                // x_{t+1} slots from register xa; prefetch x[b][t+2]
                const int b = lane - 16;
                const unsigned short hx = bf16_rtne(xa);
                const unsigned short lx = bf16_rtne(xa - bf16_f32(hx));
                unsigned* row32 = (unsigned*)&Hh[1 - p][b][0];
                row32[25] = (unsigned)hx | (0x3F80u << 16);   // k=50,51
                row32[26] = (unsigned)lx | (0x3F80u << 16);   // k=52,53
                Hh[1 - p][b][54] = hx;                        // k=54
                xa = xrow[(t + 2 < TT) ? t + 2 : TT - 1];
            }
        }

        __syncthreads();    // the ONE barrier
    }

    // epilogue: y_{TT-1}
    if (wv == NCW && lane < 16) {
        float s = bo;
        #pragma unroll
        for (int w = 0; w < NCW; ++w) s += ypart[(TT - 1) & 1][w][lane];
        yout[(size_t)lane * TT + (TT - 1)] = s;
    }
}

extern "C" void kernel_launch(void* const* d_in, const int* in_sizes, int n_in,
                              void* d_out, int out_size, void* d_ws, size_t ws_size,
                              hipStream_t stream) {
    const float* x     = (const float*)d_in[0];
    const float* W_ih  = (const float*)d_in[1];
    const float* W_hh  = (const float*)d_in[2];
    const float* b_ih  = (const float*)d_in[3];
    const float* b_hh  = (const float*)d_in[4];
    const float* W_out = (const float*)d_in[5];
    const float* b_out = (const float*)d_in[6];
    float* out = (float*)d_out;

    const int B = in_sizes[0] / TT;          // 4096
    lstm_mfma9_kernel<<<B / BT, 512, 0, stream>>>(x, W_ih, W_hh, b_ih, b_hh,
                                                  W_out, b_out, out);
}